// Round 18
// baseline (679.525 us; speedup 1.0000x reference)
//
#include <hip/hip_runtime.h>

#define NN 100000
#define EE 1600000
#define DD 128
#define TD 640
#define EPSV 1e-5f
#define NBLK_SCAN 391   // ceil(NN/256)
#define SB 1024         // stats partial blocks
#define NRANGE 8        // XCD count; node range slice = NN/8
#define RSZ 12500       // NN / NRANGE
#define NCHUNK 256      // edge chunks
#define CSZ 6250        // EE / NCHUNK
#define GB2 782         // gemm2 blocks (128-row tiles)

typedef __attribute__((ext_vector_type(8))) short bf16x8;
typedef __attribute__((ext_vector_type(4))) float f32x4;
typedef const __attribute__((address_space(1))) unsigned int gu32;
typedef __attribute__((address_space(3))) unsigned int lu32;

__device__ inline unsigned short f2b(float f) {
  union { float f; unsigned u; } x; x.f = f;
  unsigned r = x.u + 0x7fff + ((x.u >> 16) & 1);
  return (unsigned short)(r >> 16);
}
__device__ inline float b2f(unsigned short u) {
  union { unsigned u; float f; } x; x.u = ((unsigned)u) << 16;
  return x.f;
}

// ---------- PRE1: merged {curs zero | BN stats stage1 (fp32) | W->B2 cvt}
__global__ __launch_bounds__(256) void k_pre1(int* __restrict__ curs,
    const float* __restrict__ x, float* __restrict__ ps, float* __restrict__ pq,
    const float* __restrict__ w1, unsigned short* __restrict__ o1,
    const float* __restrict__ w2, unsigned short* __restrict__ o2) {
  const int bi = blockIdx.x;
  const int t = threadIdx.x;
  if (bi < NBLK_SCAN) {              // zero cursor
    int i = bi * 256 + t;
    if (i < NN) curs[i] = 0;
    return;
  }
  if (bi < NBLK_SCAN + SB) {         // stats stage-1 over features
    const int sb = bi - NBLK_SCAN;
    float s0=0.f,s1=0.f,s2=0.f,s3=0.f,q0=0.f,q1=0.f,q2=0.f,q3=0.f;
    const float4* x4 = reinterpret_cast<const float4*>(x);
    const int total = NN * DD / 4;
    for (int i = sb * 256 + t; i < total; i += SB * 256) {
      float4 v = x4[i];
      s0 += v.x; s1 += v.y; s2 += v.z; s3 += v.w;
      q0 += v.x*v.x; q1 += v.y*v.y; q2 += v.z*v.z; q3 += v.w*v.w;
    }
    __shared__ float ls[256], lq[256];
    float sv[4] = {s0,s1,s2,s3}, qv[4] = {q0,q1,q2,q3};
#pragma unroll
    for (int j = 0; j < 4; ++j) {
      ls[t] = sv[j]; lq[t] = qv[j];
      __syncthreads();
      if (t < 32) {
        float a = 0.f, b = 0.f;
#pragma unroll
        for (int k = 0; k < 8; ++k) { a += ls[t + 32*k]; b += lq[t + 32*k]; }
        ps[sb * DD + t*4 + j] = a;
        pq[sb * DD + t*4 + j] = b;
      }
      __syncthreads();
    }
    return;
  }
  // W -> B2 rearrange + bf16 + PRE-SWIZZLE:
  // B2s[d][unit u] = B2L[d][unit (u&~7)|((u&7)^(d&7))], B2L[d][t*128+k]=W[(t*128+d)*128+k]
  int cb = bi - (NBLK_SCAN + SB);    // [0,160)
  const float* w = (cb < 80) ? w1 : w2;
  unsigned short* o = (cb < 80) ? o1 : o2;
  if (cb >= 80) cb -= 80;
  int i = cb * 256 + t;              // ushort4 index [0, 20480)
  int tt = i >> 12;
  int rem = i & 4095;
  int d = rem >> 5, j = rem & 31;
  float4 v = reinterpret_cast<const float4*>(w)[i];
  ushort4 u; u.x = f2b(v.x); u.y = f2b(v.y); u.z = f2b(v.z); u.w = f2b(v.w);
  int u16 = tt * 16 + (j >> 1);
  int u16s = (u16 & ~7) | ((u16 & 7) ^ (d & 7));
  reinterpret_cast<ushort4*>(o)[d * 160 + u16s * 2 + (j & 1)] = u;
}

// ---------- PRE2: merged {hist | BN stats stage2 -> ssb}
__global__ __launch_bounds__(256) void k_pre2(const int* __restrict__ dst,
    int* __restrict__ cnt, const float* __restrict__ ps, const float* __restrict__ pq,
    const float* __restrict__ g, const float* __restrict__ be, float* __restrict__ ssb) {
  const int bi = blockIdx.x;
  const int t = threadIdx.x;
  if (bi < NRANGE * NCHUNK) {        // hist (XCD-sliced; bi&7 mapping preserved)
    const int range = bi & (NRANGE - 1);
    const int chunk = bi >> 3;
    const int lo = range * RSZ;
    const int base = chunk * CSZ;
    for (int i = base + t; i < base + CSZ; i += 256) {
      int d = dst[i];
      if ((unsigned)(d - lo) < RSZ) atomicAdd(&cnt[d], 1);
    }
    return;
  }
  // stats stage-2 (256-thread variant: 2 segs x 128 cols)
  __shared__ float ls[256], lq[256];
  int col = t & 127, seg = t >> 7;
  float s = 0.f, q = 0.f;
  for (int b = seg; b < SB; b += 2) { s += ps[b * DD + col]; q += pq[b * DD + col]; }
  ls[t] = s; lq[t] = q;
  __syncthreads();
  if (t < 128) {
    s = ls[t] + ls[t + 128]; q = lq[t] + lq[t + 128];
    float mean = s * (1.0f / NN);
    float var  = q * (1.0f / NN) - mean * mean;
    float sc = g[t] * rsqrtf(var + EPSV);
    ssb[t] = sc;
    ssb[DD + t] = be[t] - mean * sc;
  }
}

// ---------- stats stage-2 for round 2 (782 per-block partials from gemm2<0>)
__global__ __launch_bounds__(256) void k_stats_final2(const float* __restrict__ ps,
    const float* __restrict__ pq, const float* __restrict__ g,
    const float* __restrict__ be, float* __restrict__ ssb) {
  __shared__ float ls[256], lq[256];
  int t = threadIdx.x;
  int col = t & 127, seg = t >> 7;
  float s = 0.f, q = 0.f;
  for (int b = seg; b < GB2; b += 2) { s += ps[b * DD + col]; q += pq[b * DD + col]; }
  ls[t] = s; lq[t] = q;
  __syncthreads();
  if (t < 128) {
    s = ls[t] + ls[t + 128]; q = lq[t] + lq[t + 128];
    float mean = s * (1.0f / NN);
    float var  = q * (1.0f / NN) - mean * mean;
    float sc = g[t] * rsqrtf(var + EPSV);
    ssb[t] = sc;
    ssb[DD + t] = be[t] - mean * sc;
  }
}

// ---------- MID: merged {scan_fin | fused BN+ReLU+bf16 act (fp32 in)}
__global__ __launch_bounds__(256) void k_mid(const int* __restrict__ cnt,
    const int* __restrict__ bsum, int* __restrict__ row_ptr, int* __restrict__ cursor,
    const float* __restrict__ x, const float* __restrict__ ss,
    unsigned short* __restrict__ A) {
  const int bi = blockIdx.x;
  const int t = threadIdx.x;
  if (bi < NBLK_SCAN) {              // scan_fin
    __shared__ int sh[256];
    int idx = bi * 256 + t;
    int v = (idx < NN) ? cnt[idx] : 0;
    sh[t] = v;
    __syncthreads();
    for (int off = 1; off < 256; off <<= 1) {
      int add = (t >= off) ? sh[t - off] : 0;
      __syncthreads();
      sh[t] += add;
      __syncthreads();
    }
    int excl = bsum[bi] + sh[t] - v;
    if (idx < NN) { row_ptr[idx] = excl; cursor[idx] = excl; }
    if (idx == NN - 1) row_ptr[NN] = excl + v;
    return;
  }
  // act (fp32 input)
  int i = (bi - NBLK_SCAN) * 256 + t;  // [0, NN*DD/4) exactly
  float4 v = reinterpret_cast<const float4*>(x)[i];
  int c4 = (i & 31) * 4;
  float s0 = ss[c4+0], s1 = ss[c4+1], s2 = ss[c4+2], s3 = ss[c4+3];
  float h0 = ss[DD+c4+0], h1 = ss[DD+c4+1], h2 = ss[DD+c4+2], h3 = ss[DD+c4+3];
  ushort4 o;
  o.x = f2b(fmaxf(0.f, v.x * s0 + h0));
  o.y = f2b(fmaxf(0.f, v.y * s1 + h1));
  o.z = f2b(fmaxf(0.f, v.z * s2 + h2));
  o.w = f2b(fmaxf(0.f, v.w * s3 + h3));
  reinterpret_cast<ushort4*>(A)[i] = o;
}

// ---------- fused BN+ReLU+bf16 cast (bf16 input, round 2)
__global__ __launch_bounds__(256) void k_act_bf(const unsigned short* __restrict__ x,
    const float* __restrict__ ss, unsigned short* __restrict__ A) {
  int i = blockIdx.x * 256 + threadIdx.x;
  ushort4 u = reinterpret_cast<const ushort4*>(x)[i];
  int c4 = (i & 31) * 4;
  float s0 = ss[c4+0], s1 = ss[c4+1], s2 = ss[c4+2], s3 = ss[c4+3];
  float h0 = ss[DD+c4+0], h1 = ss[DD+c4+1], h2 = ss[DD+c4+2], h3 = ss[DD+c4+3];
  ushort4 o;
  o.x = f2b(fmaxf(0.f, b2f(u.x) * s0 + h0));
  o.y = f2b(fmaxf(0.f, b2f(u.y) * s1 + h1));
  o.z = f2b(fmaxf(0.f, b2f(u.z) * s2 + h2));
  o.w = f2b(fmaxf(0.f, b2f(u.w) * s3 + h3));
  reinterpret_cast<ushort4*>(A)[i] = o;
}

// ---------- scan stages 1-2
__global__ __launch_bounds__(256) void k_scan_blk(const int* __restrict__ cnt, int* __restrict__ bsum) {
  __shared__ int sh[256];
  int idx = blockIdx.x * 256 + threadIdx.x;
  sh[threadIdx.x] = (idx < NN) ? cnt[idx] : 0;
  __syncthreads();
  for (int off = 128; off > 0; off >>= 1) {
    if (threadIdx.x < off) sh[threadIdx.x] += sh[threadIdx.x + off];
    __syncthreads();
  }
  if (threadIdx.x == 0) bsum[blockIdx.x] = sh[0];
}
__global__ __launch_bounds__(512) void k_scan_top(int* __restrict__ bsum) {
  __shared__ int sh[512];
  int t = threadIdx.x;
  int v = (t < NBLK_SCAN) ? bsum[t] : 0;
  sh[t] = v;
  __syncthreads();
  for (int off = 1; off < 512; off <<= 1) {
    int add = (t >= off) ? sh[t - off] : 0;
    __syncthreads();
    sh[t] += add;
    __syncthreads();
  }
  if (t < NBLK_SCAN) bsum[t] = sh[t] - v;  // exclusive
}
__global__ __launch_bounds__(256) void k_scatter(const int* __restrict__ src,
    const int* __restrict__ dst, const int* __restrict__ et,
    int* __restrict__ cursor, int* __restrict__ payload) {
  const int range = blockIdx.x & (NRANGE - 1);
  const int chunk = blockIdx.x >> 3;
  const int lo = range * RSZ;
  const int base = chunk * CSZ;
  for (int i = base + threadIdx.x; i < base + CSZ; i += 256) {
    int d = dst[i];
    if ((unsigned)(d - lo) < RSZ) {
      int pos = atomicAdd(&cursor[d], 1);
      payload[pos] = (src[i] << 3) | et[i];
    }
  }
}

// ---------- K1: per-dst aggregate of h rows by type (exact R14/R17 code).
__global__ __launch_bounds__(256) void k_agg(const unsigned short* __restrict__ Ab,
    const int* __restrict__ rp, const int* __restrict__ pl,
    unsigned short* __restrict__ G, int* __restrict__ cntb) {
  const int n = blockIdx.x * 4 + (threadIdx.x >> 6);
  const int l = threadIdx.x & 63;
  const int s = __builtin_amdgcn_readfirstlane(rp[n]);
  const int e = __builtin_amdgcn_readfirstlane(rp[n + 1]);
  float a00=0.f,a01=0.f,a10=0.f,a11=0.f,a20=0.f,a21=0.f,a30=0.f,a31=0.f,a40=0.f,a41=0.f;
  int c0=0,c1=0,c2=0,c3=0,c4=0;
  int j = s;
#define ACC_ONE(P, U) do {                                              \
    float x0 = b2f((U).x), x1 = b2f((U).y);                             \
    switch ((P) & 7) {                                                  \
      case 0: a00 += x0; a01 += x1; c0++; break;                        \
      case 1: a10 += x0; a11 += x1; c1++; break;                        \
      case 2: a20 += x0; a21 += x1; c2++; break;                        \
      case 3: a30 += x0; a31 += x1; c3++; break;                        \
      default: a40 += x0; a41 += x1; c4++; break;                       \
    } } while (0)
  int p0=0,p1=0,p2=0,p3=0,p4=0,p5=0,p6=0,p7=0;
  if (j + 7 < e) {
    p0 = __builtin_amdgcn_readfirstlane(pl[j]);
    p1 = __builtin_amdgcn_readfirstlane(pl[j + 1]);
    p2 = __builtin_amdgcn_readfirstlane(pl[j + 2]);
    p3 = __builtin_amdgcn_readfirstlane(pl[j + 3]);
    p4 = __builtin_amdgcn_readfirstlane(pl[j + 4]);
    p5 = __builtin_amdgcn_readfirstlane(pl[j + 5]);
    p6 = __builtin_amdgcn_readfirstlane(pl[j + 6]);
    p7 = __builtin_amdgcn_readfirstlane(pl[j + 7]);
  }
  for (; j + 15 < e; j += 8) {
    ushort2 u0 = *reinterpret_cast<const ushort2*>(Ab + (p0 >> 3) * DD + 2 * l);
    ushort2 u1 = *reinterpret_cast<const ushort2*>(Ab + (p1 >> 3) * DD + 2 * l);
    ushort2 u2 = *reinterpret_cast<const ushort2*>(Ab + (p2 >> 3) * DD + 2 * l);
    ushort2 u3 = *reinterpret_cast<const ushort2*>(Ab + (p3 >> 3) * DD + 2 * l);
    ushort2 u4 = *reinterpret_cast<const ushort2*>(Ab + (p4 >> 3) * DD + 2 * l);
    ushort2 u5 = *reinterpret_cast<const ushort2*>(Ab + (p5 >> 3) * DD + 2 * l);
    ushort2 u6 = *reinterpret_cast<const ushort2*>(Ab + (p6 >> 3) * DD + 2 * l);
    ushort2 u7 = *reinterpret_cast<const ushort2*>(Ab + (p7 >> 3) * DD + 2 * l);
    int q0 = __builtin_amdgcn_readfirstlane(pl[j + 8]);
    int q1 = __builtin_amdgcn_readfirstlane(pl[j + 9]);
    int q2 = __builtin_amdgcn_readfirstlane(pl[j + 10]);
    int q3 = __builtin_amdgcn_readfirstlane(pl[j + 11]);
    int q4 = __builtin_amdgcn_readfirstlane(pl[j + 12]);
    int q5 = __builtin_amdgcn_readfirstlane(pl[j + 13]);
    int q6 = __builtin_amdgcn_readfirstlane(pl[j + 14]);
    int q7 = __builtin_amdgcn_readfirstlane(pl[j + 15]);
    ACC_ONE(p0, u0); ACC_ONE(p1, u1); ACC_ONE(p2, u2); ACC_ONE(p3, u3);
    ACC_ONE(p4, u4); ACC_ONE(p5, u5); ACC_ONE(p6, u6); ACC_ONE(p7, u7);
    p0=q0; p1=q1; p2=q2; p3=q3; p4=q4; p5=q5; p6=q6; p7=q7;
  }
  if (j + 7 < e) {
    ushort2 u0 = *reinterpret_cast<const ushort2*>(Ab + (p0 >> 3) * DD + 2 * l);
    ushort2 u1 = *reinterpret_cast<const ushort2*>(Ab + (p1 >> 3) * DD + 2 * l);
    ushort2 u2 = *reinterpret_cast<const ushort2*>(Ab + (p2 >> 3) * DD + 2 * l);
    ushort2 u3 = *reinterpret_cast<const ushort2*>(Ab + (p3 >> 3) * DD + 2 * l);
    ushort2 u4 = *reinterpret_cast<const ushort2*>(Ab + (p4 >> 3) * DD + 2 * l);
    ushort2 u5 = *reinterpret_cast<const ushort2*>(Ab + (p5 >> 3) * DD + 2 * l);
    ushort2 u6 = *reinterpret_cast<const ushort2*>(Ab + (p6 >> 3) * DD + 2 * l);
    ushort2 u7 = *reinterpret_cast<const ushort2*>(Ab + (p7 >> 3) * DD + 2 * l);
    ACC_ONE(p0, u0); ACC_ONE(p1, u1); ACC_ONE(p2, u2); ACC_ONE(p3, u3);
    ACC_ONE(p4, u4); ACC_ONE(p5, u5); ACC_ONE(p6, u6); ACC_ONE(p7, u7);
    j += 8;
  }
  for (; j < e; ++j) {
    int p = __builtin_amdgcn_readfirstlane(pl[j]);
    ushort2 u = *reinterpret_cast<const ushort2*>(Ab + (p >> 3) * DD + 2 * l);
    ACC_ONE(p, u);
  }
#undef ACC_ONE
  unsigned short* gp = G + n * TD + 2 * l;
  ushort2 o;
  o.x = f2b(a00); o.y = f2b(a01); *reinterpret_cast<ushort2*>(gp + 0 * DD) = o;
  o.x = f2b(a10); o.y = f2b(a11); *reinterpret_cast<ushort2*>(gp + 1 * DD) = o;
  o.x = f2b(a20); o.y = f2b(a21); *reinterpret_cast<ushort2*>(gp + 2 * DD) = o;
  o.x = f2b(a30); o.y = f2b(a31); *reinterpret_cast<ushort2*>(gp + 3 * DD) = o;
  o.x = f2b(a40); o.y = f2b(a41); *reinterpret_cast<ushort2*>(gp + 4 * DD) = o;
  if (l < 5) {
    int c = (l == 0) ? c0 : (l == 1) ? c1 : (l == 2) ? c2 : (l == 3) ? c3 : c4;
    cntb[n * 8 + l] = c;
  }
}

// ---------- K2: y[N,128] = G[N,640] . B2[128,640]^T + cnt*b (+ base).
// R17-proven: gload_lds async staging of pre-swizzled B2, linear LDS dest,
// read-side swizzle. RND==0 additionally accumulates per-block column
// sum/sumsq of the fp32 y1 values (round-2 BN stats stage-1, fused).
template<int RND>
__global__ __launch_bounds__(256, 4) void k_gemm2(const unsigned short* __restrict__ G,
    const unsigned short* __restrict__ B2, const float* __restrict__ bias,
    const int* __restrict__ cntb, const float* __restrict__ base,
    void* __restrict__ out, float* __restrict__ ps2, float* __restrict__ pq2) {
  __shared__ __align__(16) unsigned short wlds[2][8192];  // 2 x 16 KB: [128 cols][64 K]
  const int t = threadIdx.x;
  const int l = t & 63;
  const int w = t >> 6;
  const int lm = l & 15, hi = l >> 4;
  const int R = blockIdx.x * 128;
  const char* b2c = reinterpret_cast<const char*>(B2);

#define STAGE(BUF, KS) do {                                                    \
    _Pragma("unroll") for (int k = 0; k < 4; ++k) {                            \
      int idx = k * 256 + t;                                                   \
      int c = idx >> 3, sub = idx & 7;                                         \
      __builtin_amdgcn_global_load_lds(                                        \
          (gu32*)(b2c + c * 1280 + (KS) * 128 + sub * 16),                     \
          (lu32*)(reinterpret_cast<char*>(wlds[BUF]) + (k * 256 + (t & ~63)) * 16), \
          16, 0, 0);                                                           \
    }                                                                          \
  } while (0)

  STAGE(0, 0);
  __syncthreads();

  const unsigned short* ap[2];
#pragma unroll
  for (int rf = 0; rf < 2; ++rf) {
    int ar = R + w * 32 + rf * 16 + lm; if (ar >= NN) ar = NN - 1;
    ap[rf] = G + ar * TD + hi * 8;
  }

  f32x4 acc[2][8] = {};
#pragma unroll 1
  for (int ks = 0; ks < 10; ++ks) {
    const int buf = ks & 1;
    if (ks < 9) STAGE(buf ^ 1, ks + 1);
    bf16x8 af[2][2];
#pragma unroll
    for (int rf = 0; rf < 2; ++rf) {
      af[rf][0] = *reinterpret_cast<const bf16x8*>(ap[rf] + ks * 64);
      af[rf][1] = *reinterpret_cast<const bf16x8*>(ap[rf] + ks * 64 + 32);
    }
    char* bc = (char*)wlds[buf];
    const unsigned sw = (unsigned)((lm & 7) << 4);
#pragma unroll
    for (int cf = 0; cf < 8; ++cf) {
      int colB = cf * 16 + lm;
      bf16x8 b0 = *reinterpret_cast<const bf16x8*>(bc + colB * 128 + ((hi * 16) ^ sw));
      bf16x8 b1 = *reinterpret_cast<const bf16x8*>(bc + colB * 128 + ((64 + hi * 16) ^ sw));
#pragma unroll
      for (int rf = 0; rf < 2; ++rf) {
        acc[rf][cf] = __builtin_amdgcn_mfma_f32_16x16x32_bf16(af[rf][0], b0, acc[rf][cf], 0, 0, 0);
        acc[rf][cf] = __builtin_amdgcn_mfma_f32_16x16x32_bf16(af[rf][1], b1, acc[rf][cf], 0, 0, 0);
      }
    }
    __syncthreads();
  }
#undef STAGE

  float sv[8] = {}, qv[8] = {};
#pragma unroll
  for (int cf = 0; cf < 8; ++cf) {
    int col = cf * 16 + lm;
    float bb0 = bias[col], bb1 = bias[128 + col], bb2 = bias[256 + col],
          bb3 = bias[384 + col], bb4 = bias[512 + col];
#pragma unroll
    for (int rf = 0; rf < 2; ++rf) {
#pragma unroll
      for (int r = 0; r < 4; ++r) {
        int row = R + w * 32 + rf * 16 + hi * 4 + r;
        if (row < NN) {
          const int* cp = cntb + row * 8;
          float v = acc[rf][cf][r] + cp[0]*bb0 + cp[1]*bb1 + cp[2]*bb2 + cp[3]*bb3 + cp[4]*bb4;
          if (RND == 1) {
            v += base[row * DD + col];
            reinterpret_cast<float*>(out)[row * DD + col] = v;
          } else {
            reinterpret_cast<unsigned short*>(out)[row * DD + col] = f2b(v);
            sv[cf] += v; qv[cf] += v * v;
          }
        }
      }
    }
  }
  if (RND == 0) {
    // per-block column reduce via (now-dead) wlds: 16 partials per column
    float* rs = reinterpret_cast<float*>(wlds[0]);  // [128 cols][16]
    float* rq = reinterpret_cast<float*>(wlds[1]);
    const int slot = w * 4 + hi;
#pragma unroll
    for (int cf = 0; cf < 8; ++cf) {
      int col = cf * 16 + lm;
      rs[col * 16 + slot] = sv[cf];
      rq[col * 16 + slot] = qv[cf];
    }
    __syncthreads();
    if (t < 128) {
      float s = 0.f, q = 0.f;
#pragma unroll
      for (int k = 0; k < 16; ++k) { s += rs[t * 16 + k]; q += rq[t * 16 + k]; }
      ps2[blockIdx.x * DD + t] = s;
      pq2[blockIdx.x * DD + t] = q;
    }
  }
}

extern "C" void kernel_launch(void* const* d_in, const int* in_sizes, int n_in,
                              void* d_out, int out_size, void* d_ws, size_t ws_size,
                              hipStream_t stream) {
  const float* features = (const float*)d_in[0];
  const int*   src   = (const int*)d_in[1];
  const int*   dst   = (const int*)d_in[2];
  const int*   etype = (const int*)d_in[3];
  const float* w1  = (const float*)d_in[4];
  const float* b1  = (const float*)d_in[5];
  const float* g1  = (const float*)d_in[6];
  const float* be1 = (const float*)d_in[7];
  const float* w2  = (const float*)d_in[8];
  const float* b2  = (const float*)d_in[9];
  const float* g2  = (const float*)d_in[10];
  const float* be2 = (const float*)d_in[11];

  char* ws = (char*)d_ws;
  unsigned short* Ab   = (unsigned short*)(ws + 0);            // 25,600,000 B
  float*          ps   = (float*)(ws + 0);                     // aliases Ab (dead windows)
  float*          pq   = (float*)(ws + 524288);
  unsigned short* G    = (unsigned short*)(ws + 25600000);     // 128,000,000 B
  unsigned short* y1   = (unsigned short*)(ws + 153600000);    // 25,600,000 B (bf16)
  unsigned short* b2a  = (unsigned short*)(ws + 179200000);    // 163,840 B
  unsigned short* b2b  = (unsigned short*)(ws + 179363840);    // 163,840 B
  float*          ssb  = (float*)(ws + 179527680);             // 1,024 B
  int*            rowp = (int*)(ws + 179528704);               // 400,016 B
  int*            curs = (int*)(ws + 179928720);               // 400,000 B
  int*            payl = (int*)(ws + 180328720);               // 6,400,000 B
  int*            bsum = (int*)(ws + 186728720);               // 2,048 B
  int*            cntb = (int*)(ws + 186730768);               // 3,200,000 B
  // total: 189,930,768 B (same as passing R6..R17 layout)

  // 1: {zero curs | stats1(features) | cvt+preswizzle B2}
  k_pre1<<<NBLK_SCAN + SB + 160, 256, 0, stream>>>(curs, features, ps, pq,
                                                   w1, b2a, w2, b2b);
  // 2: {hist | stats2 -> ssb(round1)}
  k_pre2<<<NRANGE * NCHUNK + 1, 256, 0, stream>>>(dst, curs, ps, pq, g1, be1, ssb);
  k_scan_blk<<<NBLK_SCAN, 256, 0, stream>>>(curs, bsum);
  k_scan_top<<<1, 512, 0, stream>>>(bsum);
  // 5: {scan_fin | act(features -> Ab)}  (act overwrites ps/pq region: consumed by pre2)
  k_mid<<<NBLK_SCAN + 12500, 256, 0, stream>>>(curs, bsum, rowp, curs,
                                               features, ssb, Ab);
  k_scatter<<<NRANGE * NCHUNK, 256, 0, stream>>>(src, dst, etype, curs, payl);

  // ---- round 1
  k_agg<<<NN / 4, 256, 0, stream>>>(Ab, rowp, payl, G, cntb);
  // gemm2<0>: y1 + fused round-2 stats partials (ps/pq region: Ab dead here)
  k_gemm2<0><<<GB2, 256, 0, stream>>>(G, b2a, b1, cntb, nullptr, y1, ps, pq);

  // ---- round 2
  k_stats_final2<<<1, 256, 0, stream>>>(ps, pq, g2, be2, ssb);
  k_act_bf<<<12500, 256, 0, stream>>>(y1, ssb, Ab);
  k_agg<<<NN / 4, 256, 0, stream>>>(Ab, rowp, payl, G, cntb);
  k_gemm2<1><<<GB2, 256, 0, stream>>>(G, b2b, b2, cntb, features, d_out, nullptr, nullptr);
}

// Round 19
// 532.678 us; speedup vs baseline: 1.2757x; 1.2757x over previous
//
#include <hip/hip_runtime.h>

#define NN 100000
#define EE 1600000
#define DD 128
#define TD 640
#define EPSV 1e-5f
#define NBLK_SCAN 391   // ceil(NN/256)
#define SB 1024         // stats partial blocks
#define NRANGE 8        // XCD count; node range slice = NN/8
#define RSZ 12500       // NN / NRANGE
#define NCHUNK 256      // edge chunks
#define CSZ 6250        // EE / NCHUNK
#define GB2 782         // gemm2 blocks (128-row tiles)

typedef __attribute__((ext_vector_type(8))) short bf16x8;
typedef __attribute__((ext_vector_type(4))) float f32x4;
typedef const __attribute__((address_space(1))) unsigned int gu32;
typedef __attribute__((address_space(3))) unsigned int lu32;

__device__ inline unsigned short f2b(float f) {
  union { float f; unsigned u; } x; x.f = f;
  unsigned r = x.u + 0x7fff + ((x.u >> 16) & 1);
  return (unsigned short)(r >> 16);
}
__device__ inline float b2f(unsigned short u) {
  union { unsigned u; float f; } x; x.u = ((unsigned)u) << 16;
  return x.f;
}

// ---------- BN stats, stage 1 (fp32 input, round 1)
__global__ __launch_bounds__(256) void k_stats_partial(const float* __restrict__ x,
    float* __restrict__ ps, float* __restrict__ pq) {
  float s0=0.f,s1=0.f,s2=0.f,s3=0.f,q0=0.f,q1=0.f,q2=0.f,q3=0.f;
  const float4* x4 = reinterpret_cast<const float4*>(x);
  const int total = NN * DD / 4;
  for (int i = blockIdx.x * 256 + threadIdx.x; i < total; i += SB * 256) {
    float4 v = x4[i];
    s0 += v.x; s1 += v.y; s2 += v.z; s3 += v.w;
    q0 += v.x*v.x; q1 += v.y*v.y; q2 += v.z*v.z; q3 += v.w*v.w;
  }
  __shared__ float ls[256], lq[256];
  int t = threadIdx.x;
  float sv[4] = {s0,s1,s2,s3}, qv[4] = {q0,q1,q2,q3};
#pragma unroll
  for (int j = 0; j < 4; ++j) {
    ls[t] = sv[j]; lq[t] = qv[j];
    __syncthreads();
    if (t < 32) {
      float a = 0.f, b = 0.f;
#pragma unroll
      for (int k = 0; k < 8; ++k) { a += ls[t + 32*k]; b += lq[t + 32*k]; }
      ps[blockIdx.x * DD + t*4 + j] = a;
      pq[blockIdx.x * DD + t*4 + j] = b;
    }
    __syncthreads();
  }
}

// ---------- BN stats, stage 2 (round 1: SB partials)
__global__ __launch_bounds__(1024) void k_stats_final(const float* __restrict__ ps,
    const float* __restrict__ pq, const float* __restrict__ g,
    const float* __restrict__ be, float* __restrict__ ssb) {
  __shared__ float ls[1024], lq[1024];
  int t = threadIdx.x;
  int col = t & 127, seg = t >> 7;
  float s = 0.f, q = 0.f;
  for (int b = seg; b < SB; b += 8) { s += ps[b * DD + col]; q += pq[b * DD + col]; }
  ls[t] = s; lq[t] = q;
  __syncthreads();
  if (t < 128) {
#pragma unroll
    for (int k = 1; k < 8; ++k) { s += ls[t + 128*k]; q += lq[t + 128*k]; }
    float mean = s * (1.0f / NN);
    float var  = q * (1.0f / NN) - mean * mean;
    float sc = g[t] * rsqrtf(var + EPSV);
    ssb[t] = sc;
    ssb[DD + t] = be[t] - mean * sc;
  }
}

// ---------- BN stats, stage 2 (round 2: GB2 partials from gemm2<0> epilogue)
__global__ __launch_bounds__(1024) void k_stats_final2(const float* __restrict__ ps,
    const float* __restrict__ pq, const float* __restrict__ g,
    const float* __restrict__ be, float* __restrict__ ssb) {
  __shared__ float ls[1024], lq[1024];
  int t = threadIdx.x;
  int col = t & 127, seg = t >> 7;
  float s = 0.f, q = 0.f;
  for (int b = seg; b < GB2; b += 8) { s += ps[b * DD + col]; q += pq[b * DD + col]; }
  ls[t] = s; lq[t] = q;
  __syncthreads();
  if (t < 128) {
#pragma unroll
    for (int k = 1; k < 8; ++k) { s += ls[t + 128*k]; q += lq[t + 128*k]; }
    float mean = s * (1.0f / NN);
    float var  = q * (1.0f / NN) - mean * mean;
    float sc = g[t] * rsqrtf(var + EPSV);
    ssb[t] = sc;
    ssb[DD + t] = be[t] - mean * sc;
  }
}

// ---------- fused BN+ReLU+bf16 cast (fp32 input)
__global__ __launch_bounds__(256) void k_act(const float* __restrict__ x,
    const float* __restrict__ ss, unsigned short* __restrict__ A) {
  int i = blockIdx.x * 256 + threadIdx.x;  // [0, NN*DD/4) exactly
  float4 v = reinterpret_cast<const float4*>(x)[i];
  int c4 = (i & 31) * 4;
  float s0 = ss[c4+0], s1 = ss[c4+1], s2 = ss[c4+2], s3 = ss[c4+3];
  float h0 = ss[DD+c4+0], h1 = ss[DD+c4+1], h2 = ss[DD+c4+2], h3 = ss[DD+c4+3];
  ushort4 o;
  o.x = f2b(fmaxf(0.f, v.x * s0 + h0));
  o.y = f2b(fmaxf(0.f, v.y * s1 + h1));
  o.z = f2b(fmaxf(0.f, v.z * s2 + h2));
  o.w = f2b(fmaxf(0.f, v.w * s3 + h3));
  reinterpret_cast<ushort4*>(A)[i] = o;
}

// ---------- fused BN+ReLU+bf16 cast (bf16 input, round 2)
__global__ __launch_bounds__(256) void k_act_bf(const unsigned short* __restrict__ x,
    const float* __restrict__ ss, unsigned short* __restrict__ A) {
  int i = blockIdx.x * 256 + threadIdx.x;
  ushort4 u = reinterpret_cast<const ushort4*>(x)[i];
  int c4 = (i & 31) * 4;
  float s0 = ss[c4+0], s1 = ss[c4+1], s2 = ss[c4+2], s3 = ss[c4+3];
  float h0 = ss[DD+c4+0], h1 = ss[DD+c4+1], h2 = ss[DD+c4+2], h3 = ss[DD+c4+3];
  ushort4 o;
  o.x = f2b(fmaxf(0.f, b2f(u.x) * s0 + h0));
  o.y = f2b(fmaxf(0.f, b2f(u.y) * s1 + h1));
  o.z = f2b(fmaxf(0.f, b2f(u.z) * s2 + h2));
  o.w = f2b(fmaxf(0.f, b2f(u.w) * s3 + h3));
  reinterpret_cast<ushort4*>(A)[i] = o;
}

// ---------- W -> B2 rearrange + bf16 + PRE-SWIZZLE (both weights, one launch).
// B2s[d][unit u] = B2L[d][unit (u&~7)|((u&7)^(d&7))], B2L[d][t*128+k]=W[(t*128+d)*128+k]
__global__ void k_cvt_b2(const float* __restrict__ w1, unsigned short* __restrict__ o1,
                         const float* __restrict__ w2, unsigned short* __restrict__ o2) {
  int bi = blockIdx.x;
  const float* w = (bi < 80) ? w1 : w2;
  unsigned short* o = (bi < 80) ? o1 : o2;
  if (bi >= 80) bi -= 80;
  int i = bi * 256 + threadIdx.x;  // ushort4 index [0, 20480)
  int tt = i >> 12;
  int rem = i & 4095;
  int d = rem >> 5, j = rem & 31;
  float4 v = reinterpret_cast<const float4*>(w)[i];
  ushort4 u; u.x = f2b(v.x); u.y = f2b(v.y); u.z = f2b(v.z); u.w = f2b(v.w);
  int u16 = tt * 16 + (j >> 1);
  int u16s = (u16 & ~7) | ((u16 & 7) ^ (d & 7));
  reinterpret_cast<ushort4*>(o)[d * 160 + u16s * 2 + (j & 1)] = u;
}

// ---------- CSR build
__global__ void k_zero(int* p, int n) {
  int i = blockIdx.x * 256 + threadIdx.x;
  if (i < n) p[i] = 0;
}
__global__ __launch_bounds__(256) void k_hist(const int* __restrict__ dst,
    int* __restrict__ cnt) {
  const int range = blockIdx.x & (NRANGE - 1);
  const int chunk = blockIdx.x >> 3;
  const int lo = range * RSZ;
  const int base = chunk * CSZ;
  for (int i = base + threadIdx.x; i < base + CSZ; i += 256) {
    int d = dst[i];
    if ((unsigned)(d - lo) < RSZ) atomicAdd(&cnt[d], 1);
  }
}
__global__ __launch_bounds__(256) void k_scan_blk(const int* __restrict__ cnt, int* __restrict__ bsum) {
  __shared__ int sh[256];
  int idx = blockIdx.x * 256 + threadIdx.x;
  sh[threadIdx.x] = (idx < NN) ? cnt[idx] : 0;
  __syncthreads();
  for (int off = 128; off > 0; off >>= 1) {
    if (threadIdx.x < off) sh[threadIdx.x] += sh[threadIdx.x + off];
    __syncthreads();
  }
  if (threadIdx.x == 0) bsum[blockIdx.x] = sh[0];
}
__global__ __launch_bounds__(512) void k_scan_top(int* __restrict__ bsum) {
  __shared__ int sh[512];
  int t = threadIdx.x;
  int v = (t < NBLK_SCAN) ? bsum[t] : 0;
  sh[t] = v;
  __syncthreads();
  for (int off = 1; off < 512; off <<= 1) {
    int add = (t >= off) ? sh[t - off] : 0;
    __syncthreads();
    sh[t] += add;
    __syncthreads();
  }
  if (t < NBLK_SCAN) bsum[t] = sh[t] - v;  // exclusive
}
__global__ __launch_bounds__(256) void k_scan_fin(const int* __restrict__ cnt,
    const int* __restrict__ bsum, int* __restrict__ row_ptr, int* __restrict__ cursor) {
  __shared__ int sh[256];
  int idx = blockIdx.x * 256 + threadIdx.x;
  int v = (idx < NN) ? cnt[idx] : 0;
  sh[threadIdx.x] = v;
  __syncthreads();
  for (int off = 1; off < 256; off <<= 1) {
    int add = (threadIdx.x >= off) ? sh[threadIdx.x - off] : 0;
    __syncthreads();
    sh[threadIdx.x] += add;
    __syncthreads();
  }
  int excl = bsum[blockIdx.x] + sh[threadIdx.x] - v;
  if (idx < NN) { row_ptr[idx] = excl; cursor[idx] = excl; }
  if (idx == NN - 1) row_ptr[NN] = excl + v;
}
__global__ __launch_bounds__(256) void k_scatter(const int* __restrict__ src,
    const int* __restrict__ dst, const int* __restrict__ et,
    int* __restrict__ cursor, int* __restrict__ payload) {
  const int range = blockIdx.x & (NRANGE - 1);
  const int chunk = blockIdx.x >> 3;
  const int lo = range * RSZ;
  const int base = chunk * CSZ;
  for (int i = base + threadIdx.x; i < base + CSZ; i += 256) {
    int d = dst[i];
    if ((unsigned)(d - lo) < RSZ) {
      int pos = atomicAdd(&cursor[d], 1);
      payload[pos] = (src[i] << 3) | et[i];
    }
  }
}

// ---------- K1: per-dst aggregate of h rows by type (exact R14/R17 code).
__global__ __launch_bounds__(256) void k_agg(const unsigned short* __restrict__ Ab,
    const int* __restrict__ rp, const int* __restrict__ pl,
    unsigned short* __restrict__ G, int* __restrict__ cntb) {
  const int n = blockIdx.x * 4 + (threadIdx.x >> 6);
  const int l = threadIdx.x & 63;
  const int s = __builtin_amdgcn_readfirstlane(rp[n]);
  const int e = __builtin_amdgcn_readfirstlane(rp[n + 1]);
  float a00=0.f,a01=0.f,a10=0.f,a11=0.f,a20=0.f,a21=0.f,a30=0.f,a31=0.f,a40=0.f,a41=0.f;
  int c0=0,c1=0,c2=0,c3=0,c4=0;
  int j = s;
#define ACC_ONE(P, U) do {                                              \
    float x0 = b2f((U).x), x1 = b2f((U).y);                             \
    switch ((P) & 7) {                                                  \
      case 0: a00 += x0; a01 += x1; c0++; break;                        \
      case 1: a10 += x0; a11 += x1; c1++; break;                        \
      case 2: a20 += x0; a21 += x1; c2++; break;                        \
      case 3: a30 += x0; a31 += x1; c3++; break;                        \
      default: a40 += x0; a41 += x1; c4++; break;                       \
    } } while (0)
  int p0=0,p1=0,p2=0,p3=0,p4=0,p5=0,p6=0,p7=0;
  if (j + 7 < e) {
    p0 = __builtin_amdgcn_readfirstlane(pl[j]);
    p1 = __builtin_amdgcn_readfirstlane(pl[j + 1]);
    p2 = __builtin_amdgcn_readfirstlane(pl[j + 2]);
    p3 = __builtin_amdgcn_readfirstlane(pl[j + 3]);
    p4 = __builtin_amdgcn_readfirstlane(pl[j + 4]);
    p5 = __builtin_amdgcn_readfirstlane(pl[j + 5]);
    p6 = __builtin_amdgcn_readfirstlane(pl[j + 6]);
    p7 = __builtin_amdgcn_readfirstlane(pl[j + 7]);
  }
  for (; j + 15 < e; j += 8) {
    ushort2 u0 = *reinterpret_cast<const ushort2*>(Ab + (p0 >> 3) * DD + 2 * l);
    ushort2 u1 = *reinterpret_cast<const ushort2*>(Ab + (p1 >> 3) * DD + 2 * l);
    ushort2 u2 = *reinterpret_cast<const ushort2*>(Ab + (p2 >> 3) * DD + 2 * l);
    ushort2 u3 = *reinterpret_cast<const ushort2*>(Ab + (p3 >> 3) * DD + 2 * l);
    ushort2 u4 = *reinterpret_cast<const ushort2*>(Ab + (p4 >> 3) * DD + 2 * l);
    ushort2 u5 = *reinterpret_cast<const ushort2*>(Ab + (p5 >> 3) * DD + 2 * l);
    ushort2 u6 = *reinterpret_cast<const ushort2*>(Ab + (p6 >> 3) * DD + 2 * l);
    ushort2 u7 = *reinterpret_cast<const ushort2*>(Ab + (p7 >> 3) * DD + 2 * l);
    int q0 = __builtin_amdgcn_readfirstlane(pl[j + 8]);
    int q1 = __builtin_amdgcn_readfirstlane(pl[j + 9]);
    int q2 = __builtin_amdgcn_readfirstlane(pl[j + 10]);
    int q3 = __builtin_amdgcn_readfirstlane(pl[j + 11]);
    int q4 = __builtin_amdgcn_readfirstlane(pl[j + 12]);
    int q5 = __builtin_amdgcn_readfirstlane(pl[j + 13]);
    int q6 = __builtin_amdgcn_readfirstlane(pl[j + 14]);
    int q7 = __builtin_amdgcn_readfirstlane(pl[j + 15]);
    ACC_ONE(p0, u0); ACC_ONE(p1, u1); ACC_ONE(p2, u2); ACC_ONE(p3, u3);
    ACC_ONE(p4, u4); ACC_ONE(p5, u5); ACC_ONE(p6, u6); ACC_ONE(p7, u7);
    p0=q0; p1=q1; p2=q2; p3=q3; p4=q4; p5=q5; p6=q6; p7=q7;
  }
  if (j + 7 < e) {
    ushort2 u0 = *reinterpret_cast<const ushort2*>(Ab + (p0 >> 3) * DD + 2 * l);
    ushort2 u1 = *reinterpret_cast<const ushort2*>(Ab + (p1 >> 3) * DD + 2 * l);
    ushort2 u2 = *reinterpret_cast<const ushort2*>(Ab + (p2 >> 3) * DD + 2 * l);
    ushort2 u3 = *reinterpret_cast<const ushort2*>(Ab + (p3 >> 3) * DD + 2 * l);
    ushort2 u4 = *reinterpret_cast<const ushort2*>(Ab + (p4 >> 3) * DD + 2 * l);
    ushort2 u5 = *reinterpret_cast<const ushort2*>(Ab + (p5 >> 3) * DD + 2 * l);
    ushort2 u6 = *reinterpret_cast<const ushort2*>(Ab + (p6 >> 3) * DD + 2 * l);
    ushort2 u7 = *reinterpret_cast<const ushort2*>(Ab + (p7 >> 3) * DD + 2 * l);
    ACC_ONE(p0, u0); ACC_ONE(p1, u1); ACC_ONE(p2, u2); ACC_ONE(p3, u3);
    ACC_ONE(p4, u4); ACC_ONE(p5, u5); ACC_ONE(p6, u6); ACC_ONE(p7, u7);
    j += 8;
  }
  for (; j < e; ++j) {
    int p = __builtin_amdgcn_readfirstlane(pl[j]);
    ushort2 u = *reinterpret_cast<const ushort2*>(Ab + (p >> 3) * DD + 2 * l);
    ACC_ONE(p, u);
  }
#undef ACC_ONE
  unsigned short* gp = G + n * TD + 2 * l;
  ushort2 o;
  o.x = f2b(a00); o.y = f2b(a01); *reinterpret_cast<ushort2*>(gp + 0 * DD) = o;
  o.x = f2b(a10); o.y = f2b(a11); *reinterpret_cast<ushort2*>(gp + 1 * DD) = o;
  o.x = f2b(a20); o.y = f2b(a21); *reinterpret_cast<ushort2*>(gp + 2 * DD) = o;
  o.x = f2b(a30); o.y = f2b(a31); *reinterpret_cast<ushort2*>(gp + 3 * DD) = o;
  o.x = f2b(a40); o.y = f2b(a41); *reinterpret_cast<ushort2*>(gp + 4 * DD) = o;
  if (l < 5) {
    int c = (l == 0) ? c0 : (l == 1) ? c1 : (l == 2) ? c2 : (l == 3) ? c3 : c4;
    cntb[n * 8 + l] = c;
  }
}

// ---------- K2: y[N,128] = G[N,640] . B2[128,640]^T + cnt*b (+ base).
// R17-proven: gload_lds async staging of pre-swizzled B2, linear LDS dest,
// read-side swizzle. RND==0 additionally emits per-block column sum/sumsq
// of the fp32 y1 values (round-2 BN stats stage-1, fused; R18-validated).
template<int RND>
__global__ __launch_bounds__(256, 4) void k_gemm2(const unsigned short* __restrict__ G,
    const unsigned short* __restrict__ B2, const float* __restrict__ bias,
    const int* __restrict__ cntb, const float* __restrict__ base,
    void* __restrict__ out, float* __restrict__ ps2, float* __restrict__ pq2) {
  __shared__ __align__(16) unsigned short wlds[2][8192];  // 2 x 16 KB: [128 cols][64 K]
  const int t = threadIdx.x;
  const int l = t & 63;
  const int w = t >> 6;
  const int lm = l & 15, hi = l >> 4;
  const int R = blockIdx.x * 128;
  const char* b2c = reinterpret_cast<const char*>(B2);

#define STAGE(BUF, KS) do {                                                    \
    _Pragma("unroll") for (int k = 0; k < 4; ++k) {                            \
      int idx = k * 256 + t;                                                   \
      int c = idx >> 3, sub = idx & 7;                                         \
      __builtin_amdgcn_global_load_lds(                                        \
          (gu32*)(b2c + c * 1280 + (KS) * 128 + sub * 16),                     \
          (lu32*)(reinterpret_cast<char*>(wlds[BUF]) + (k * 256 + (t & ~63)) * 16), \
          16, 0, 0);                                                           \
    }                                                                          \
  } while (0)

  STAGE(0, 0);
  __syncthreads();

  const unsigned short* ap[2];
#pragma unroll
  for (int rf = 0; rf < 2; ++rf) {
    int ar = R + w * 32 + rf * 16 + lm; if (ar >= NN) ar = NN - 1;
    ap[rf] = G + ar * TD + hi * 8;
  }

  f32x4 acc[2][8] = {};
#pragma unroll 1
  for (int ks = 0; ks < 10; ++ks) {
    const int buf = ks & 1;
    if (ks < 9) STAGE(buf ^ 1, ks + 1);
    bf16x8 af[2][2];
#pragma unroll
    for (int rf = 0; rf < 2; ++rf) {
      af[rf][0] = *reinterpret_cast<const bf16x8*>(ap[rf] + ks * 64);
      af[rf][1] = *reinterpret_cast<const bf16x8*>(ap[rf] + ks * 64 + 32);
    }
    char* bc = (char*)wlds[buf];
    const unsigned sw = (unsigned)((lm & 7) << 4);
#pragma unroll
    for (int cf = 0; cf < 8; ++cf) {
      int colB = cf * 16 + lm;
      bf16x8 b0 = *reinterpret_cast<const bf16x8*>(bc + colB * 128 + ((hi * 16) ^ sw));
      bf16x8 b1 = *reinterpret_cast<const bf16x8*>(bc + colB * 128 + ((64 + hi * 16) ^ sw));
#pragma unroll
      for (int rf = 0; rf < 2; ++rf) {
        acc[rf][cf] = __builtin_amdgcn_mfma_f32_16x16x32_bf16(af[rf][0], b0, acc[rf][cf], 0, 0, 0);
        acc[rf][cf] = __builtin_amdgcn_mfma_f32_16x16x32_bf16(af[rf][1], b1, acc[rf][cf], 0, 0, 0);
      }
    }
    __syncthreads();
  }
#undef STAGE

  float sv[8] = {}, qv[8] = {};
#pragma unroll
  for (int cf = 0; cf < 8; ++cf) {
    int col = cf * 16 + lm;
    float bb0 = bias[col], bb1 = bias[128 + col], bb2 = bias[256 + col],
          bb3 = bias[384 + col], bb4 = bias[512 + col];
#pragma unroll
    for (int rf = 0; rf < 2; ++rf) {
#pragma unroll
      for (int r = 0; r < 4; ++r) {
        int row = R + w * 32 + rf * 16 + hi * 4 + r;
        if (row < NN) {
          const int* cp = cntb + row * 8;
          float v = acc[rf][cf][r] + cp[0]*bb0 + cp[1]*bb1 + cp[2]*bb2 + cp[3]*bb3 + cp[4]*bb4;
          if (RND == 1) {
            v += base[row * DD + col];
            reinterpret_cast<float*>(out)[row * DD + col] = v;
          } else {
            reinterpret_cast<unsigned short*>(out)[row * DD + col] = f2b(v);
            sv[cf] += v; qv[cf] += v * v;
          }
        }
      }
    }
  }
  if (RND == 0) {
    // per-block column reduce via (now-dead) wlds: 16 partials per column
    float* rs = reinterpret_cast<float*>(wlds[0]);  // [128 cols][16]
    float* rq = reinterpret_cast<float*>(wlds[1]);
    const int slot = w * 4 + hi;
#pragma unroll
    for (int cf = 0; cf < 8; ++cf) {
      int col = cf * 16 + lm;
      rs[col * 16 + slot] = sv[cf];
      rq[col * 16 + slot] = qv[cf];
    }
    __syncthreads();
    if (t < 128) {
      float s = 0.f, q = 0.f;
#pragma unroll
      for (int k = 0; k < 16; ++k) { s += rs[t * 16 + k]; q += rq[t * 16 + k]; }
      ps2[blockIdx.x * DD + t] = s;
      pq2[blockIdx.x * DD + t] = q;
    }
  }
}

extern "C" void kernel_launch(void* const* d_in, const int* in_sizes, int n_in,
                              void* d_out, int out_size, void* d_ws, size_t ws_size,
                              hipStream_t stream) {
  const float* features = (const float*)d_in[0];
  const int*   src   = (const int*)d_in[1];
  const int*   dst   = (const int*)d_in[2];
  const int*   etype = (const int*)d_in[3];
  const float* w1  = (const float*)d_in[4];
  const float* b1  = (const float*)d_in[5];
  const float* g1  = (const float*)d_in[6];
  const float* be1 = (const float*)d_in[7];
  const float* w2  = (const float*)d_in[8];
  const float* b2  = (const float*)d_in[9];
  const float* g2  = (const float*)d_in[10];
  const float* be2 = (const float*)d_in[11];

  char* ws = (char*)d_ws;
  unsigned short* Ab   = (unsigned short*)(ws + 0);            // 25,600,000 B
  float*          ps   = (float*)(ws + 0);                     // aliases Ab (dead windows)
  float*          pq   = (float*)(ws + 524288);
  unsigned short* G    = (unsigned short*)(ws + 25600000);     // 128,000,000 B
  unsigned short* y1   = (unsigned short*)(ws + 153600000);    // 25,600,000 B (bf16)
  unsigned short* b2a  = (unsigned short*)(ws + 179200000);    // 163,840 B
  unsigned short* b2b  = (unsigned short*)(ws + 179363840);    // 163,840 B
  float*          ssb  = (float*)(ws + 179527680);             // 1,024 B
  int*            rowp = (int*)(ws + 179528704);               // 400,016 B
  int*            curs = (int*)(ws + 179928720);               // 400,000 B
  int*            payl = (int*)(ws + 180328720);               // 6,400,000 B
  int*            bsum = (int*)(ws + 186728720);               // 2,048 B
  int*            cntb = (int*)(ws + 186730768);               // 3,200,000 B
  // total: 189,930,768 B (same as passing R6..R17 layout)

  // CSR build (shared by both rounds)
  k_zero<<<(NN + 255) / 256, 256, 0, stream>>>(curs, NN);
  k_hist<<<NRANGE * NCHUNK, 256, 0, stream>>>(dst, curs);
  k_scan_blk<<<NBLK_SCAN, 256, 0, stream>>>(curs, bsum);
  k_scan_top<<<1, 512, 0, stream>>>(bsum);
  k_scan_fin<<<NBLK_SCAN, 256, 0, stream>>>(curs, bsum, rowp, curs);
  k_scatter<<<NRANGE * NCHUNK, 256, 0, stream>>>(src, dst, etype, curs, payl);

  // weights -> rearranged + pre-swizzled bf16 B2 (both in one launch)
  k_cvt_b2<<<160, 256, 0, stream>>>(w1, b2a, w2, b2b);

  // ---- round 1
  k_stats_partial<<<SB, 256, 0, stream>>>(features, ps, pq);
  k_stats_final<<<1, 1024, 0, stream>>>(ps, pq, g1, be1, ssb);
  k_act<<<12500, 256, 0, stream>>>(features, ssb, Ab);
  k_agg<<<NN / 4, 256, 0, stream>>>(Ab, rowp, payl, G, cntb);
  // gemm2<0>: y1 + fused round-2 stats partials (ps/pq region: Ab dead here)
  k_gemm2<0><<<GB2, 256, 0, stream>>>(G, b2a, b1, cntb, nullptr, y1, ps, pq);

  // ---- round 2
  k_stats_final2<<<1, 1024, 0, stream>>>(ps, pq, g2, be2, ssb);
  k_act_bf<<<12500, 256, 0, stream>>>(y1, ssb, Ab);
  k_agg<<<NN / 4, 256, 0, stream>>>(Ab, rowp, payl, G, cntb);
  k_gemm2<1><<<GB2, 256, 0, stream>>>(G, b2b, b2, cntb, features, d_out, nullptr, nullptr);
}